// Round 4
// baseline (373.992 us; speedup 1.0000x reference)
//
#include <hip/hip_runtime.h>

#define R_ 8
#define N_ 4096
#define D_ 128
#define BM 64          // rows per block
#define BKO 128        // outer K step (f32 elems) -> 512 B contiguous per adj row
#define KSPLIT 2
#define NSTEP ((N_ / KSPLIT) / BKO)   // 16

typedef __attribute__((ext_vector_type(8))) short bf16x8;
typedef __attribute__((ext_vector_type(4))) float f32x4;

__device__ __forceinline__ unsigned short f2bf(float f) {
  unsigned int u = __builtin_bit_cast(unsigned int, f);
  u += 0x7FFFu + ((u >> 16) & 1u);   // RNE
  return (unsigned short)(u >> 16);
}
__device__ __forceinline__ unsigned int pk2(float lo, float hi) {
  return (unsigned int)f2bf(lo) | ((unsigned int)f2bf(hi) << 16);
}

// async global->LDS, 16 B/lane; LDS dest = wave-uniform base + lane*16
__device__ __forceinline__ void gld16(const void* g, void* l) {
  using GP = const __attribute__((address_space(1))) unsigned int*;
  using LP = __attribute__((address_space(3))) unsigned int*;
  __builtin_amdgcn_global_load_lds((GP)g, (LP)l, 16, 0, 0);
}

// embT[d][n] = bf16(emb[n][d]) via LDS tile transpose (coalesced both sides)
__global__ __launch_bounds__(256) void k_init_embT(const float* __restrict__ emb,
                                                   unsigned short* __restrict__ embT) {
  __shared__ unsigned short t[D_][33];
  const int b = blockIdx.x;            // 128 blocks, 32 n-rows each
  const int tid = threadIdx.x;
#pragma unroll
  for (int j = 0; j < 16; ++j) {
    int flat = j * 256 + tid;          // 0..4095 over [32 n][128 d]
    int nl = flat >> 7, d = flat & 127;
    t[d][nl] = f2bf(emb[((size_t)(b * 32 + nl)) * D_ + d]);
  }
  __syncthreads();
#pragma unroll
  for (int j = 0; j < 16; ++j) {
    int flat = j * 256 + tid;          // over [128 d][32 n]
    int d = flat >> 5, nl = flat & 31;
    embT[(size_t)d * N_ + b * 32 + nl] = t[d][nl];
  }
}

__global__ void k_init_rel(const float* __restrict__ rel, unsigned short* __restrict__ relb) {
  int i = blockIdx.x * 256 + threadIdx.x;     // over R*D*D
  relb[i] = f2bf(rel[i]);
}

// agg_p[z][r][n][d] = sum_{k in z-half} adj[r][n][k] * emb[k][d]  (bf16 partials)
__global__ __launch_bounds__(256, 4) void gcn_gemm(
    const float* __restrict__ adj,            // [R][N][N] fp32
    const unsigned short* __restrict__ embT,  // [D][N] bf16 (B^T layout, L2-resident)
    unsigned short* __restrict__ agg_p)       // [KSPLIT][R][N][D] bf16
{
  // A tile only; linear rows of 128 f32 (512 B); content XOR-swizzled per 16B slot
  __shared__ float As[BM * BKO];              // 32 KB

  const int tid  = threadIdx.x;
  const int lane = tid & 63;
  const int w    = tid >> 6;
  const int wr = w >> 1, wc = w & 1;          // 2x2 waves: 32 rows x 64 cols
  const int fr  = lane & 15;
  const int k8  = (lane >> 4) * 8;            // 0,8,16,24
  const int cr4 = (lane >> 4) * 4;

  const int row0 = blockIdx.x * BM;
  const int r    = blockIdx.y;
  const int z    = blockIdx.z;
  const int k0   = z * (N_ / KSPLIT);

  // ---- A DMA map: 8 instrs/wave, each 1 KB = 2 rows x 512 B ----
  const int b1 = lane >> 5;                   // which of the 2 rows in this instr
  const int c  = lane & 31;                   // 16B slot within the row
  const float* gA = adj + ((size_t)r * N_ + row0 + w * 16 + b1) * N_ + k0;
  float* lA = As + (w * 16) * BKO;

  f32x4 acc[2][4];
#pragma unroll
  for (int m = 0; m < 2; ++m)
#pragma unroll
    for (int n = 0; n < 4; ++n)
      acc[m][n] = (f32x4){0.f, 0.f, 0.f, 0.f};

  for (int t = 0; t < NSTEP; ++t) {
    const int ko = t * BKO;
    // stage A tile: source carries the swizzle, LDS dest linear (rule #21)
#pragma unroll
    for (int i = 0; i < 8; ++i) {
      const int slot = c ^ ((2 * i + b1) & 7);
      gld16(gA + (size_t)(2 * i) * N_ + ko + slot * 4, lA + 2 * i * BKO);
    }
    __syncthreads();                          // drains vmcnt -> tile resident

#pragma unroll
    for (int kk = 0; kk < 4; ++kk) {
      bf16x8 af[2], bfr[4];
#pragma unroll
      for (int m = 0; m < 2; ++m) {
        const int row = wr * 32 + m * 16 + fr;
        const int cb  = kk * 8 + (k8 >> 2);   // even 16B-slot index
        f32x4 a0 = *(const f32x4*)&As[row * BKO + (((cb + 0) ^ (row & 7)) * 4)];
        f32x4 a1 = *(const f32x4*)&As[row * BKO + (((cb + 1) ^ (row & 7)) * 4)];
        unsigned int* ap = (unsigned int*)&af[m];
        ap[0] = pk2(a0.x, a0.y); ap[1] = pk2(a0.z, a0.w);
        ap[2] = pk2(a1.x, a1.y); ap[3] = pk2(a1.z, a1.w);
      }
#pragma unroll
      for (int n = 0; n < 4; ++n) {
        const int d = wc * 64 + n * 16 + fr;
        bfr[n] = *(const bf16x8*)&embT[(size_t)d * N_ + k0 + ko + kk * 32 + k8];
      }
#pragma unroll
      for (int m = 0; m < 2; ++m)
#pragma unroll
        for (int n = 0; n < 4; ++n)
          acc[m][n] = __builtin_amdgcn_mfma_f32_16x16x32_bf16(af[m], bfr[n], acc[m][n], 0, 0, 0);
    }
    __syncthreads();                          // protect LDS overwrite next step
  }

  // store bf16 partial tile
  unsigned short* gO = agg_p + (((size_t)z * R_ + r) * N_ + row0) * D_;
#pragma unroll
  for (int m = 0; m < 2; ++m)
#pragma unroll
    for (int n = 0; n < 4; ++n)
#pragma unroll
      for (int j = 0; j < 4; ++j) {
        int rl = wr * 32 + m * 16 + cr4 + j;
        int cl = wc * 64 + n * 16 + fr;
        gO[(size_t)rl * D_ + cl] = f2bf(acc[m][n][j]);
      }
}

// Pass 2: tmp = agg_p @ rel^T summed over z,r; out = relu(mean_r); embT for next layer
__global__ __launch_bounds__(256) void gcn_pass2(
    const unsigned short* __restrict__ agg_p,  // [KSPLIT][R][N][D] bf16
    const unsigned short* __restrict__ relb,   // [R][D][D] bf16
    float* __restrict__ out,                   // [N][D] f32
    unsigned short* __restrict__ embT,         // [D][N] bf16
    int write_out, int write_embT)
{
  const int tid  = threadIdx.x;
  const int lane = tid & 63;
  const int w    = tid >> 6;
  const int n0   = blockIdx.x * 16;
  const int col0 = w * 32;
  const int fr   = lane & 15;
  const int e8   = (lane >> 4) * 8;
  const int cr4  = (lane >> 4) * 4;

  f32x4 tacc[2];
  tacc[0] = (f32x4){0.f, 0.f, 0.f, 0.f};
  tacc[1] = (f32x4){0.f, 0.f, 0.f, 0.f};

  for (int r = 0; r < R_; ++r) {
    bf16x8 a[2][4], b[2][4];
#pragma unroll
    for (int zz = 0; zz < 2; ++zz)
#pragma unroll
      for (int kk = 0; kk < 4; ++kk)
        a[zz][kk] = *(const bf16x8*)&agg_p[(((size_t)zz * R_ + r) * N_ + n0 + fr) * D_ + kk * 32 + e8];
#pragma unroll
    for (int n = 0; n < 2; ++n)
#pragma unroll
      for (int kk = 0; kk < 4; ++kk)
        b[n][kk] = *(const bf16x8*)&relb[(size_t)r * D_ * D_ + (col0 + n * 16 + fr) * D_ + kk * 32 + e8];
#pragma unroll
    for (int n = 0; n < 2; ++n)
#pragma unroll
      for (int kk = 0; kk < 4; ++kk)
#pragma unroll
        for (int zz = 0; zz < 2; ++zz)
          tacc[n] = __builtin_amdgcn_mfma_f32_16x16x32_bf16(a[zz][kk], b[n][kk], tacc[n], 0, 0, 0);
  }

#pragma unroll
  for (int n = 0; n < 2; ++n)
#pragma unroll
    for (int j = 0; j < 4; ++j) {
      int row = n0 + cr4 + j;
      int col = col0 + n * 16 + fr;
      float v = tacc[n][j] * 0.125f;
      v = v > 0.f ? v : 0.f;
      if (write_out)  out[(size_t)row * D_ + col] = v;
      if (write_embT) embT[(size_t)col * N_ + row] = f2bf(v);
    }
}

extern "C" void kernel_launch(void* const* d_in, const int* in_sizes, int n_in,
                              void* d_out, int out_size, void* d_ws, size_t ws_size,
                              hipStream_t stream) {
  const float* adj = (const float*)d_in[0];   // [R][N][N]
  const float* emb = (const float*)d_in[1];   // [N][D]
  const float* rel = (const float*)d_in[2];   // [R][D][D]
  float* out = (float*)d_out;                 // [N][D] f32

  unsigned short* embT  = (unsigned short*)d_ws;                 // 1 MB
  unsigned short* relb  = embT + (size_t)N_ * D_;                // 256 KB
  unsigned short* agg_p = relb + (size_t)R_ * D_ * D_;           // 16 MB

  k_init_embT<<<N_ / 32, 256, 0, stream>>>(emb, embT);
  k_init_rel<<<(R_ * D_ * D_) / 256, 256, 0, stream>>>(rel, relb);

  dim3 grid(N_ / BM, R_, KSPLIT);
  for (int layer = 0; layer < 2; ++layer) {
    gcn_gemm<<<grid, 256, 0, stream>>>(adj, embT, agg_p);
    gcn_pass2<<<N_ / 16, 256, 0, stream>>>(agg_p, relb, out, embT,
                                           /*write_out=*/layer == 1,
                                           /*write_embT=*/layer == 0);
  }
}